// Round 7
// baseline (60.550 us; speedup 1.0000x reference)
//
#include <hip/hip_runtime.h>
#include <hip/hip_fp16.h>
#include <math.h>

#define NRAYS 16384
#define NPTS  256
#define GS    160
#define GS3   (GS*GS*GS)
#define BINS  64

// ACT_SHIFT = log(1/(1-1e-6) - 1) computed in double precision
#define ACT_SHIFT (-13.815509557963774f)
#define LOG2E     (1.4426950408889634f)

__device__ __forceinline__ unsigned int pack2h(float a, float b) {
    __half2 h = __halves2half2(__float2half_rn(a), __float2half_rn(b));
    return *reinterpret_cast<unsigned int*>(&h);
}

// splat float -> half2 with a single v_cvt_pkrtz_f16_f32
__device__ __forceinline__ __half2 splat_h2(float x) {
    auto v = __builtin_amdgcn_cvt_pkrtz(x, x);   // <2 x half>
    return *reinterpret_cast<__half2*>(&v);
}

__device__ __forceinline__ __half2 as_h2(unsigned int u) {
    return *reinterpret_cast<__half2*>(&u);
}

// ---- repack: SoA f32 grids -> fp16 AoS y-pair grid ----
// entry[z][y][x] (16B) = {d,r}(z,y,x), {g,b}(z,y,x), {d,r}(z,y+1,x), {g,b}(z,y+1,x)
__global__ __launch_bounds__(256)
void repack_ypairs_kernel(const float* __restrict__ dgrid,
                          const float* __restrict__ cgrid,
                          uint4* __restrict__ out)
{
    const int i = blockIdx.x * 256 + threadIdx.x;
    if (i >= GS3) return;
    const int y  = (i / GS) % GS;
    const int iy = (y < GS - 1) ? i + GS : i;   // (z, y+1, x); dup at y edge (never sampled)

    uint4 v;
    v.x = pack2h(dgrid[i],         cgrid[i]);
    v.y = pack2h(cgrid[GS3 + i],   cgrid[2*GS3 + i]);
    v.z = pack2h(dgrid[iy],        cgrid[iy]);
    v.w = pack2h(cgrid[GS3 + iy],  cgrid[2*GS3 + iy]);
    out[i] = v;
}

// ---- sample with per-block t-sort: lanes process t-adjacent points so each
// gather instruction's 64 lanes hit only ~8-12 distinct cache lines instead of ~64
// (L1/TA serializes one distinct-line lookup per cycle per instruction).
// Results staged in LDS, written back fully coalesced in natural order.
__global__ __launch_bounds__(256)
void sample_sorted_kernel(const float* __restrict__ origins,
                          const float* __restrict__ directions,
                          const float* __restrict__ lengths,
                          const uint4* __restrict__ grid,
                          float* __restrict__ out_density,
                          float* __restrict__ out_color)
{
    const int r   = blockIdx.x;
    const int tid = threadIdx.x;
    const int base = r * NPTS;

    __shared__ unsigned int  hist[BINS];
    __shared__ unsigned int  boff[BINS];
    __shared__ unsigned short sortedIdx[NPTS];
    __shared__ float lds_t[NPTS];
    __shared__ float lds_den[NPTS];
    __shared__ float lds_col[NPTS * 3];

    if (tid < BINS) hist[tid] = 0;
    const float t_own = lengths[base + tid];
    __syncthreads();

    // counting-sort key: t is ~U[0,1]
    int key = (int)(t_own * (float)BINS);
    key = min(max(key, 0), BINS - 1);
    const unsigned int rank = atomicAdd(&hist[key], 1u);
    lds_t[tid] = t_own;
    __syncthreads();

    // exclusive scan of 64 bins by the first wave (wave64 -> no extra barrier inside)
    if (tid < 64) {
        unsigned int v = hist[tid];
        #pragma unroll
        for (int off = 1; off < 64; off <<= 1) {
            unsigned int n = __shfl_up(v, (unsigned int)off, 64);
            if (tid >= off) v += n;
        }
        boff[tid] = v - hist[tid];   // exclusive prefix
    }
    __syncthreads();

    sortedIdx[boff[key] + rank] = (unsigned short)tid;
    __syncthreads();

    // this thread processes the point with sorted rank == tid
    const int src = sortedIdx[tid];
    const float t = lds_t[src];

    const float ox = origins[3*r+0], oy = origins[3*r+1], oz = origins[3*r+2];
    const float dx = directions[3*r+0], dy = directions[3*r+1], dz = directions[3*r+2];
    const float interval = sqrtf(dx*dx + dy*dy + dz*dz);

    const float x = ox + dx*t;
    const float y = oy + dy*t;
    const float z = oz + dz*t;

    // map [-1,1] -> [0, GS-1] (align_corners=True)
    const float half_sm1 = 0.5f * (float)(GS - 1);
    const float px = (x + 1.0f) * half_sm1;
    const float py = (y + 1.0f) * half_sm1;
    const float pz = (z + 1.0f) * half_sm1;

    const float fx = floorf(px), fy = floorf(py), fz = floorf(pz);
    const float wx1 = px - fx, wy1 = py - fy, wz1 = pz - fz;
    const float wx0 = 1.0f - wx1, wy0 = 1.0f - wy1, wz0 = 1.0f - wz1;

    int x0 = (int)fx, y0 = (int)fy, z0 = (int)fz;
    x0 = min(max(x0, 0), GS-2);
    y0 = min(max(y0, 0), GS-2);
    z0 = min(max(z0, 0), GS-2);

    const int i0 = ((z0  )*GS + y0)*GS + x0;   // entry (z0, y0, x0)
    const int i1 = ((z0+1)*GS + y0)*GS + x0;   // entry (z1, y0, x0)

    // issue all 4 16B gathers before consuming (max MLP)
    const uint4 e00 = grid[i0];        // z0, x0  (rows y0, y0+1)
    const uint4 e01 = grid[i0 + 1];    // z0, x1
    const uint4 e10 = grid[i1];        // z1, x0
    const uint4 e11 = grid[i1 + 1];    // z1, x1

    // 8 corner weights, splatted to half2 (computed while loads are in flight)
    const float wz0y0 = wz0*wy0, wz0y1 = wz0*wy1;
    const float wz1y0 = wz1*wy0, wz1y1 = wz1*wy1;
    const __half2 w000 = splat_h2(wz0y0*wx0), w001 = splat_h2(wz0y0*wx1);
    const __half2 w010 = splat_h2(wz0y1*wx0), w011 = splat_h2(wz0y1*wx1);
    const __half2 w100 = splat_h2(wz1y0*wx0), w101 = splat_h2(wz1y0*wx1);
    const __half2 w110 = splat_h2(wz1y1*wx0), w111 = splat_h2(wz1y1*wx1);

    __half2 acc_dr = splat_h2(0.0f);
    __half2 acc_gb = acc_dr;
    acc_dr = __hfma2(as_h2(e00.x), w000, acc_dr);  // (z0,y0,x0)
    acc_gb = __hfma2(as_h2(e00.y), w000, acc_gb);
    acc_dr = __hfma2(as_h2(e00.z), w010, acc_dr);  // (z0,y1,x0)
    acc_gb = __hfma2(as_h2(e00.w), w010, acc_gb);
    acc_dr = __hfma2(as_h2(e01.x), w001, acc_dr);  // (z0,y0,x1)
    acc_gb = __hfma2(as_h2(e01.y), w001, acc_gb);
    acc_dr = __hfma2(as_h2(e01.z), w011, acc_dr);  // (z0,y1,x1)
    acc_gb = __hfma2(as_h2(e01.w), w011, acc_gb);
    acc_dr = __hfma2(as_h2(e10.x), w100, acc_dr);  // (z1,y0,x0)
    acc_gb = __hfma2(as_h2(e10.y), w100, acc_gb);
    acc_dr = __hfma2(as_h2(e10.z), w110, acc_dr);  // (z1,y1,x0)
    acc_gb = __hfma2(as_h2(e10.w), w110, acc_gb);
    acc_dr = __hfma2(as_h2(e11.x), w101, acc_dr);  // (z1,y0,x1)
    acc_gb = __hfma2(as_h2(e11.y), w101, acc_gb);
    acc_dr = __hfma2(as_h2(e11.z), w111, acc_dr);  // (z1,y1,x1)
    acc_gb = __hfma2(as_h2(e11.w), w111, acc_gb);

    const float s0 = __low2float(acc_dr);
    const float s1 = __high2float(acc_dr);
    const float s2 = __low2float(acc_gb);
    const float s3 = __high2float(acc_gb);

    // density = 1 - (1+e^a)^(-interval) = 1 - 2^(-interval * log2(1 + 2^(a*log2e)))
    const float a  = s0 + ACT_SHIFT;
    const float ea = __builtin_amdgcn_exp2f(LOG2E * a);
    const float L  = __builtin_amdgcn_logf(1.0f + ea);
    const float den = 1.0f - __builtin_amdgcn_exp2f(-interval * L);

    const float e1 = __builtin_amdgcn_exp2f(-LOG2E * s1);
    const float e2 = __builtin_amdgcn_exp2f(-LOG2E * s2);
    const float e3 = __builtin_amdgcn_exp2f(-LOG2E * s3);

    // stage at the point's natural slot
    lds_den[src] = den;
    lds_col[src*3 + 0] = __builtin_amdgcn_rcpf(1.0f + e1);
    lds_col[src*3 + 1] = __builtin_amdgcn_rcpf(1.0f + e2);
    lds_col[src*3 + 2] = __builtin_amdgcn_rcpf(1.0f + e3);
    __syncthreads();

    // fully coalesced writes in natural order
    out_density[base + tid] = lds_den[tid];
    const int cb = base * 3;
    out_color[cb + tid      ] = lds_col[tid      ];
    out_color[cb + tid + 256] = lds_col[tid + 256];
    out_color[cb + tid + 512] = lds_col[tid + 512];
}

// ---------------- fallback: direct SoA sampling (round-2 kernel) ----------------
__device__ __forceinline__ float2 ld2(const float* p) {
    return *reinterpret_cast<const float2*>(p);
}

__global__ __launch_bounds__(256)
void dvgo_render_kernel(const float* __restrict__ origins,
                        const float* __restrict__ directions,
                        const float* __restrict__ lengths,
                        const float* __restrict__ dgrid,
                        const float* __restrict__ cgrid,
                        float* __restrict__ out_density,
                        float* __restrict__ out_color)
{
    const int r = blockIdx.x;
    const int p = threadIdx.x;
    const int idx = r * NPTS + p;

    const float t  = lengths[idx];
    const float ox = origins[3*r+0], oy = origins[3*r+1], oz = origins[3*r+2];
    const float dx = directions[3*r+0], dy = directions[3*r+1], dz = directions[3*r+2];
    const float interval = sqrtf(dx*dx + dy*dy + dz*dz);

    const float x = ox + dx*t;
    const float y = oy + dy*t;
    const float z = oz + dz*t;

    const float half_sm1 = 0.5f * (float)(GS - 1);
    const float px = (x + 1.0f) * half_sm1;
    const float py = (y + 1.0f) * half_sm1;
    const float pz = (z + 1.0f) * half_sm1;

    const float fx = floorf(px), fy = floorf(py), fz = floorf(pz);
    const float wx1 = px - fx, wy1 = py - fy, wz1 = pz - fz;
    const float wx0 = 1.0f - wx1, wy0 = 1.0f - wy1, wz0 = 1.0f - wz1;

    int x0 = (int)fx, y0 = (int)fy, z0 = (int)fz;
    x0 = min(max(x0, 0), GS-2);
    y0 = min(max(y0, 0), GS-2);
    z0 = min(max(z0, 0), GS-2);

    int rows[4];
    rows[0] = ((z0  )*GS + y0  )*GS + x0;
    rows[1] = ((z0  )*GS + y0+1)*GS + x0;
    rows[2] = ((z0+1)*GS + y0  )*GS + x0;
    rows[3] = ((z0+1)*GS + y0+1)*GS + x0;

    const float* bases[4] = {dgrid, cgrid, cgrid + GS3, cgrid + 2*GS3};

    float2 v[4][4];
    #pragma unroll
    for (int ch = 0; ch < 4; ++ch)
        #pragma unroll
        for (int rr = 0; rr < 4; ++rr)
            v[ch][rr] = ld2(bases[ch] + rows[rr]);

    float rw[4];
    rw[0] = wz0*wy0; rw[1] = wz0*wy1; rw[2] = wz1*wy0; rw[3] = wz1*wy1;

    float s[4];
    #pragma unroll
    for (int ch = 0; ch < 4; ++ch) {
        float acc = 0.0f;
        #pragma unroll
        for (int rr = 0; rr < 4; ++rr)
            acc = fmaf(rw[rr], fmaf(v[ch][rr].x, wx0, v[ch][rr].y * wx1), acc);
        s[ch] = acc;
    }

    const float a  = s[0] + ACT_SHIFT;
    const float sp = (a > 20.0f) ? a : log1pf(__expf(a));
    out_density[idx] = 1.0f - __expf(-interval * sp);

    #pragma unroll
    for (int c = 0; c < 3; ++c)
        out_color[idx*3 + c] = 1.0f / (1.0f + __expf(-s[c+1]));
}

extern "C" void kernel_launch(void* const* d_in, const int* in_sizes, int n_in,
                              void* d_out, int out_size, void* d_ws, size_t ws_size,
                              hipStream_t stream) {
    const float* origins    = (const float*)d_in[0];
    const float* directions = (const float*)d_in[1];
    const float* lengths    = (const float*)d_in[2];
    const float* dgrid      = (const float*)d_in[3];
    const float* cgrid      = (const float*)d_in[4];

    float* out_density = (float*)d_out;               // [R, P, 1]
    float* out_color   = (float*)d_out + NRAYS*NPTS;  // [R, P, 3]

    if (ws_size >= (size_t)GS3 * sizeof(uint4)) {
        uint4* pairs = (uint4*)d_ws;
        repack_ypairs_kernel<<<(GS3 + 255) / 256, 256, 0, stream>>>(dgrid, cgrid, pairs);
        sample_sorted_kernel<<<NRAYS, NPTS, 0, stream>>>(
            origins, directions, lengths, pairs, out_density, out_color);
    } else {
        dvgo_render_kernel<<<NRAYS, NPTS, 0, stream>>>(
            origins, directions, lengths, dgrid, cgrid, out_density, out_color);
    }
}

// Round 8
// 59.585 us; speedup vs baseline: 1.0162x; 1.0162x over previous
//
#include <hip/hip_runtime.h>
#include <hip/hip_fp16.h>
#include <math.h>

#define NRAYS 16384
#define NPTS  256
#define GS    160
#define GS3   (GS*GS*GS)
#define BINS  64

// ACT_SHIFT = log(1/(1-1e-6) - 1) computed in double precision
#define ACT_SHIFT (-13.815509557963774f)
#define LOG2E     (1.4426950408889634f)

typedef float floatx2 __attribute__((ext_vector_type(2)));

// pack 4 floats -> 4 fp8 e4m3 (OCP on gfx950) in one dword, HW RNE rounding
__device__ __forceinline__ unsigned int pack4fp8(float d, float r, float g, float b) {
    int w = __builtin_amdgcn_cvt_pk_fp8_f32(d, r, 0, false);   // bytes 0,1
    w     = __builtin_amdgcn_cvt_pk_fp8_f32(g, b, w, true);    // bytes 2,3
    return (unsigned int)w;
}

// unpack one corner word (4 fp8 channels) and accumulate with corner weight
__device__ __forceinline__ void acc4(unsigned int w, float cw,
                                     float& s0, float& s1, float& s2, float& s3) {
    floatx2 dr = __builtin_amdgcn_cvt_pk_f32_fp8((int)w, false);  // d, r
    floatx2 gb = __builtin_amdgcn_cvt_pk_f32_fp8((int)w, true);   // g, b
    s0 = fmaf(cw, dr.x, s0);
    s1 = fmaf(cw, dr.y, s1);
    s2 = fmaf(cw, gb.x, s2);
    s3 = fmaf(cw, gb.y, s3);
}

// ---- repack: SoA f32 grids -> fp8 xy-quad grid ----
// entry[z][y][x] (16B) = corner words {d,r,g,b} at (y0,x0),(y1,x0),(y0,x1),(y1,x1).
// A point needs only entries (z0,y0,x0) and (z1,y0,x0): 2 aligned dwordx4 gathers.
__global__ __launch_bounds__(256)
void repack_fp8quad_kernel(const float* __restrict__ dgrid,
                           const float* __restrict__ cgrid,
                           uint4* __restrict__ out)
{
    const int i = blockIdx.x * 256 + threadIdx.x;
    if (i >= GS3) return;
    const int x = i % GS;
    const int y = (i / GS) % GS;
    const int ox = (x < GS - 1) ? 1  : 0;   // x+1 (dup at edge, never sampled)
    const int oy = (y < GS - 1) ? GS : 0;   // y+1

    const int i00 = i, i10 = i + oy, i01 = i + ox, i11 = i + oy + ox;

    uint4 v;
    v.x = pack4fp8(dgrid[i00], cgrid[i00], cgrid[GS3 + i00], cgrid[2*GS3 + i00]);
    v.y = pack4fp8(dgrid[i10], cgrid[i10], cgrid[GS3 + i10], cgrid[2*GS3 + i10]);
    v.z = pack4fp8(dgrid[i01], cgrid[i01], cgrid[GS3 + i01], cgrid[2*GS3 + i01]);
    v.w = pack4fp8(dgrid[i11], cgrid[i11], cgrid[GS3 + i11], cgrid[2*GS3 + i11]);
    out[i] = v;
}

// ---- sample: 2 divergent gathers/point (the instruction count is the cost),
// per-block t-sort for locality + coalesced writes, channel-major LDS staging ----
__global__ __launch_bounds__(256)
void sample_fp8_sorted_kernel(const float* __restrict__ origins,
                              const float* __restrict__ directions,
                              const float* __restrict__ lengths,
                              const uint4* __restrict__ grid,
                              float* __restrict__ out_density,
                              float* __restrict__ out_color)
{
    const int r   = blockIdx.x;
    const int tid = threadIdx.x;
    const int base = r * NPTS;

    __shared__ unsigned int   hist[BINS];
    __shared__ unsigned int   boff[BINS];
    __shared__ unsigned short sortedIdx[NPTS];
    __shared__ float lds_t[NPTS];
    __shared__ float lds_den[NPTS];
    __shared__ float lds_r[NPTS];
    __shared__ float lds_g[NPTS];
    __shared__ float lds_b[NPTS];

    if (tid < BINS) hist[tid] = 0;
    const float t_own = lengths[base + tid];
    __syncthreads();

    int key = (int)(t_own * (float)BINS);
    key = min(max(key, 0), BINS - 1);
    const unsigned int rank = atomicAdd(&hist[key], 1u);
    lds_t[tid] = t_own;
    __syncthreads();

    // exclusive scan of 64 bins by the first wave
    if (tid < 64) {
        unsigned int v = hist[tid];
        #pragma unroll
        for (int off = 1; off < 64; off <<= 1) {
            unsigned int n = __shfl_up(v, (unsigned int)off, 64);
            if (tid >= off) v += n;
        }
        boff[tid] = v - hist[tid];
    }
    __syncthreads();

    sortedIdx[boff[key] + rank] = (unsigned short)tid;
    __syncthreads();

    const int src = sortedIdx[tid];
    const float t = lds_t[src];

    const float ox = origins[3*r+0], oy = origins[3*r+1], oz = origins[3*r+2];
    const float dx = directions[3*r+0], dy = directions[3*r+1], dz = directions[3*r+2];
    const float interval = sqrtf(dx*dx + dy*dy + dz*dz);

    const float xw = ox + dx*t;
    const float yw = oy + dy*t;
    const float zw = oz + dz*t;

    // map [-1,1] -> [0, GS-1] (align_corners=True)
    const float half_sm1 = 0.5f * (float)(GS - 1);
    const float px = (xw + 1.0f) * half_sm1;
    const float py = (yw + 1.0f) * half_sm1;
    const float pz = (zw + 1.0f) * half_sm1;

    const float fx = floorf(px), fy = floorf(py), fz = floorf(pz);
    const float wx1 = px - fx, wy1 = py - fy, wz1 = pz - fz;
    const float wx0 = 1.0f - wx1, wy0 = 1.0f - wy1, wz0 = 1.0f - wz1;

    int x0 = (int)fx, y0 = (int)fy, z0 = (int)fz;
    x0 = min(max(x0, 0), GS-2);
    y0 = min(max(y0, 0), GS-2);
    z0 = min(max(z0, 0), GS-2);

    const int i0 = (z0*GS + y0)*GS + x0;
    const int i1 = i0 + GS*GS;

    // the two gathers (all 8 corners x 4 channels)
    const uint4 ez0 = grid[i0];
    const uint4 ez1 = grid[i1];

    // corner weights (computed while loads are in flight)
    const float cw00 = wy0*wx0, cw10 = wy1*wx0, cw01 = wy0*wx1, cw11 = wy1*wx1;

    float s0 = 0.f, s1 = 0.f, s2 = 0.f, s3 = 0.f;
    acc4(ez0.x, wz0*cw00, s0, s1, s2, s3);
    acc4(ez0.y, wz0*cw10, s0, s1, s2, s3);
    acc4(ez0.z, wz0*cw01, s0, s1, s2, s3);
    acc4(ez0.w, wz0*cw11, s0, s1, s2, s3);
    acc4(ez1.x, wz1*cw00, s0, s1, s2, s3);
    acc4(ez1.y, wz1*cw10, s0, s1, s2, s3);
    acc4(ez1.z, wz1*cw01, s0, s1, s2, s3);
    acc4(ez1.w, wz1*cw11, s0, s1, s2, s3);

    // density = 1 - (1+e^a)^(-interval) = 1 - 2^(-interval * log2(1 + 2^(a*log2e)))
    const float a  = s0 + ACT_SHIFT;
    const float ea = __builtin_amdgcn_exp2f(LOG2E * a);
    const float L  = __builtin_amdgcn_logf(1.0f + ea);
    const float den = 1.0f - __builtin_amdgcn_exp2f(-interval * L);

    const float e1 = __builtin_amdgcn_exp2f(-LOG2E * s1);
    const float e2 = __builtin_amdgcn_exp2f(-LOG2E * s2);
    const float e3 = __builtin_amdgcn_exp2f(-LOG2E * s3);

    // channel-major staging (separate arrays -> near-conflict-free scatter)
    lds_den[src] = den;
    lds_r[src] = __builtin_amdgcn_rcpf(1.0f + e1);
    lds_g[src] = __builtin_amdgcn_rcpf(1.0f + e2);
    lds_b[src] = __builtin_amdgcn_rcpf(1.0f + e3);
    __syncthreads();

    // fully coalesced writes in natural order
    out_density[base + tid] = lds_den[tid];
    const int cb = base * 3;
    #pragma unroll
    for (int k = 0; k < 3; ++k) {
        const int o  = k * NPTS + tid;
        const int pp = o / 3;
        const int cc = o - pp * 3;
        const float vr = lds_r[pp], vg = lds_g[pp], vb = lds_b[pp];
        out_color[cb + o] = (cc == 0) ? vr : ((cc == 1) ? vg : vb);
    }
}

// ---------------- fallback: direct SoA sampling (round-2 kernel) ----------------
__device__ __forceinline__ float2 ld2(const float* p) {
    return *reinterpret_cast<const float2*>(p);
}

__global__ __launch_bounds__(256)
void dvgo_render_kernel(const float* __restrict__ origins,
                        const float* __restrict__ directions,
                        const float* __restrict__ lengths,
                        const float* __restrict__ dgrid,
                        const float* __restrict__ cgrid,
                        float* __restrict__ out_density,
                        float* __restrict__ out_color)
{
    const int r = blockIdx.x;
    const int p = threadIdx.x;
    const int idx = r * NPTS + p;

    const float t  = lengths[idx];
    const float ox = origins[3*r+0], oy = origins[3*r+1], oz = origins[3*r+2];
    const float dx = directions[3*r+0], dy = directions[3*r+1], dz = directions[3*r+2];
    const float interval = sqrtf(dx*dx + dy*dy + dz*dz);

    const float x = ox + dx*t;
    const float y = oy + dy*t;
    const float z = oz + dz*t;

    const float half_sm1 = 0.5f * (float)(GS - 1);
    const float px = (x + 1.0f) * half_sm1;
    const float py = (y + 1.0f) * half_sm1;
    const float pz = (z + 1.0f) * half_sm1;

    const float fx = floorf(px), fy = floorf(py), fz = floorf(pz);
    const float wx1 = px - fx, wy1 = py - fy, wz1 = pz - fz;
    const float wx0 = 1.0f - wx1, wy0 = 1.0f - wy1, wz0 = 1.0f - wz1;

    int x0 = (int)fx, y0 = (int)fy, z0 = (int)fz;
    x0 = min(max(x0, 0), GS-2);
    y0 = min(max(y0, 0), GS-2);
    z0 = min(max(z0, 0), GS-2);

    int rows[4];
    rows[0] = ((z0  )*GS + y0  )*GS + x0;
    rows[1] = ((z0  )*GS + y0+1)*GS + x0;
    rows[2] = ((z0+1)*GS + y0  )*GS + x0;
    rows[3] = ((z0+1)*GS + y0+1)*GS + x0;

    const float* bases[4] = {dgrid, cgrid, cgrid + GS3, cgrid + 2*GS3};

    float2 v[4][4];
    #pragma unroll
    for (int ch = 0; ch < 4; ++ch)
        #pragma unroll
        for (int rr = 0; rr < 4; ++rr)
            v[ch][rr] = ld2(bases[ch] + rows[rr]);

    float rw[4];
    rw[0] = wz0*wy0; rw[1] = wz0*wy1; rw[2] = wz1*wy0; rw[3] = wz1*wy1;

    float s[4];
    #pragma unroll
    for (int ch = 0; ch < 4; ++ch) {
        float acc = 0.0f;
        #pragma unroll
        for (int rr = 0; rr < 4; ++rr)
            acc = fmaf(rw[rr], fmaf(v[ch][rr].x, wx0, v[ch][rr].y * wx1), acc);
        s[ch] = acc;
    }

    const float a  = s[0] + ACT_SHIFT;
    const float sp = (a > 20.0f) ? a : log1pf(__expf(a));
    out_density[idx] = 1.0f - __expf(-interval * sp);

    #pragma unroll
    for (int c = 0; c < 3; ++c)
        out_color[idx*3 + c] = 1.0f / (1.0f + __expf(-s[c+1]));
}

extern "C" void kernel_launch(void* const* d_in, const int* in_sizes, int n_in,
                              void* d_out, int out_size, void* d_ws, size_t ws_size,
                              hipStream_t stream) {
    const float* origins    = (const float*)d_in[0];
    const float* directions = (const float*)d_in[1];
    const float* lengths    = (const float*)d_in[2];
    const float* dgrid      = (const float*)d_in[3];
    const float* cgrid      = (const float*)d_in[4];

    float* out_density = (float*)d_out;               // [R, P, 1]
    float* out_color   = (float*)d_out + NRAYS*NPTS;  // [R, P, 3]

    if (ws_size >= (size_t)GS3 * sizeof(uint4)) {
        uint4* quads = (uint4*)d_ws;
        repack_fp8quad_kernel<<<(GS3 + 255) / 256, 256, 0, stream>>>(dgrid, cgrid, quads);
        sample_fp8_sorted_kernel<<<NRAYS, NPTS, 0, stream>>>(
            origins, directions, lengths, quads, out_density, out_color);
    } else {
        dvgo_render_kernel<<<NRAYS, NPTS, 0, stream>>>(
            origins, directions, lengths, dgrid, cgrid, out_density, out_color);
    }
}

// Round 9
// 57.709 us; speedup vs baseline: 1.0492x; 1.0325x over previous
//
#include <hip/hip_runtime.h>
#include <hip/hip_fp16.h>
#include <math.h>

#define NRAYS 16384
#define NPTS  256
#define GS    160
#define GS3   (GS*GS*GS)
#define BINS  64

// ACT_SHIFT = log(1/(1-1e-6) - 1) computed in double precision
#define ACT_SHIFT (-13.815509557963774f)
#define LOG2E     (1.4426950408889634f)

typedef float floatx2 __attribute__((ext_vector_type(2)));

// pack 4 floats -> 4 fp8 e4m3 (OCP on gfx950) in one dword, HW RNE rounding
__device__ __forceinline__ unsigned int pack4fp8(float d, float r, float g, float b) {
    int w = __builtin_amdgcn_cvt_pk_fp8_f32(d, r, 0, false);   // bytes 0,1
    w     = __builtin_amdgcn_cvt_pk_fp8_f32(g, b, w, true);    // bytes 2,3
    return (unsigned int)w;
}

// unpack one corner word (4 fp8 channels), packed-f32 accumulate (v_pk_fma_f32)
__device__ __forceinline__ void acc2(unsigned int w, float cw,
                                     floatx2& sdr, floatx2& sgb) {
    floatx2 dr = __builtin_amdgcn_cvt_pk_f32_fp8((int)w, false);  // d, r
    floatx2 gb = __builtin_amdgcn_cvt_pk_f32_fp8((int)w, true);   // g, b
    floatx2 cw2 = {cw, cw};
    sdr += dr * cw2;
    sgb += gb * cw2;
}

// ---- repack: SoA f32 grids -> fp8 xy-quad grid ----
// entry[z][y][x] (16B) = corner words {d,r,g,b} at (y0,x0),(y1,x0),(y0,x1),(y1,x1).
// A point needs only entries (z0,y0,x0) and (z1,y0,x0): 2 aligned dwordx4 gathers.
__global__ __launch_bounds__(256)
void repack_fp8quad_kernel(const float* __restrict__ dgrid,
                           const float* __restrict__ cgrid,
                           uint4* __restrict__ out)
{
    const int i = blockIdx.x * 256 + threadIdx.x;
    if (i >= GS3) return;
    const int x = i % GS;
    const int y = (i / GS) % GS;
    const int ox = (x < GS - 1) ? 1  : 0;   // x+1 (dup at edge, never sampled)
    const int oy = (y < GS - 1) ? GS : 0;   // y+1

    const int i00 = i, i10 = i + oy, i01 = i + ox, i11 = i + oy + ox;

    uint4 v;
    v.x = pack4fp8(dgrid[i00], cgrid[i00], cgrid[GS3 + i00], cgrid[2*GS3 + i00]);
    v.y = pack4fp8(dgrid[i10], cgrid[i10], cgrid[GS3 + i10], cgrid[2*GS3 + i10]);
    v.z = pack4fp8(dgrid[i01], cgrid[i01], cgrid[GS3 + i01], cgrid[2*GS3 + i01]);
    v.w = pack4fp8(dgrid[i11], cgrid[i11], cgrid[GS3 + i11], cgrid[2*GS3 + i11]);
    out[i] = v;
}

// ---- sample: 128 threads/block, 2 points/thread (adjacent sorted ranks).
// Per-block counting sort of t gives per-wave gather locality + coalesced writes;
// 2 pts/thread halves sort/barrier overhead per point and doubles gather MLP.
__global__ __launch_bounds__(128)
void sample_fp8_x2_kernel(const float* __restrict__ origins,
                          const float* __restrict__ directions,
                          const float* __restrict__ lengths,
                          const uint4* __restrict__ grid,
                          float* __restrict__ out_density,
                          float* __restrict__ out_color)
{
    const int r   = blockIdx.x;
    const int tid = threadIdx.x;          // 0..127
    const int base = r * NPTS;

    __shared__ unsigned int   hist[BINS];
    __shared__ unsigned int   boff[BINS];
    __shared__ unsigned short sortedIdx[NPTS];
    __shared__ float lds_t[NPTS];
    __shared__ float lds_den[NPTS];
    __shared__ float lds_r[NPTS];
    __shared__ float lds_g[NPTS];
    __shared__ float lds_b[NPTS];

    if (tid < BINS) hist[tid] = 0;
    const float ta = lengths[base + tid];
    const float tb = lengths[base + tid + 128];
    __syncthreads();

    int ka = min(max((int)(ta * (float)BINS), 0), BINS - 1);
    int kb = min(max((int)(tb * (float)BINS), 0), BINS - 1);
    const unsigned int ra_ = atomicAdd(&hist[ka], 1u);
    const unsigned int rb_ = atomicAdd(&hist[kb], 1u);
    lds_t[tid]       = ta;
    lds_t[tid + 128] = tb;
    __syncthreads();

    // exclusive scan of 64 bins by the first wave
    if (tid < 64) {
        unsigned int v = hist[tid];
        #pragma unroll
        for (int off = 1; off < 64; off <<= 1) {
            unsigned int n = __shfl_up(v, (unsigned int)off, 64);
            if (tid >= off) v += n;
        }
        boff[tid] = v - hist[tid];
    }
    __syncthreads();

    sortedIdx[boff[ka] + ra_] = (unsigned short)tid;
    sortedIdx[boff[kb] + rb_] = (unsigned short)(tid + 128);
    __syncthreads();

    // this thread processes adjacent sorted ranks 2*tid, 2*tid+1
    const int src0 = sortedIdx[2*tid];
    const int src1 = sortedIdx[2*tid + 1];
    const float t0 = lds_t[src0];
    const float t1 = lds_t[src1];

    const float ox = origins[3*r+0], oy = origins[3*r+1], oz = origins[3*r+2];
    const float dx = directions[3*r+0], dy = directions[3*r+1], dz = directions[3*r+2];
    const float interval = sqrtf(dx*dx + dy*dy + dz*dz);
    const float half_sm1 = 0.5f * (float)(GS - 1);

    // ---- addresses for both points first, then issue all 4 gathers ----
    float pxA, pyA, pzA, pxB, pyB, pzB;
    {
        pxA = (ox + dx*t0 + 1.0f) * half_sm1;
        pyA = (oy + dy*t0 + 1.0f) * half_sm1;
        pzA = (oz + dz*t0 + 1.0f) * half_sm1;
        pxB = (ox + dx*t1 + 1.0f) * half_sm1;
        pyB = (oy + dy*t1 + 1.0f) * half_sm1;
        pzB = (oz + dz*t1 + 1.0f) * half_sm1;
    }

    const float fxA = floorf(pxA), fyA = floorf(pyA), fzA = floorf(pzA);
    const float fxB = floorf(pxB), fyB = floorf(pyB), fzB = floorf(pzB);

    int xA = min(max((int)fxA, 0), GS-2);
    int yA = min(max((int)fyA, 0), GS-2);
    int zA = min(max((int)fzA, 0), GS-2);
    int xB = min(max((int)fxB, 0), GS-2);
    int yB = min(max((int)fyB, 0), GS-2);
    int zB = min(max((int)fzB, 0), GS-2);

    const int iA0 = (zA*GS + yA)*GS + xA;
    const int iB0 = (zB*GS + yB)*GS + xB;

    const uint4 eA0 = grid[iA0];
    const uint4 eA1 = grid[iA0 + GS*GS];
    const uint4 eB0 = grid[iB0];
    const uint4 eB1 = grid[iB0 + GS*GS];

    // weights (computed while loads are in flight)
    const float wxA1 = pxA - fxA, wyA1 = pyA - fyA, wzA1 = pzA - fzA;
    const float wxA0 = 1.0f - wxA1, wyA0 = 1.0f - wyA1, wzA0 = 1.0f - wzA1;
    const float wxB1 = pxB - fxB, wyB1 = pyB - fyB, wzB1 = pzB - fzB;
    const float wxB0 = 1.0f - wxB1, wyB0 = 1.0f - wyB1, wzB0 = 1.0f - wzB1;

    const float cA00 = wyA0*wxA0, cA10 = wyA1*wxA0, cA01 = wyA0*wxA1, cA11 = wyA1*wxA1;
    const float cB00 = wyB0*wxB0, cB10 = wyB1*wxB0, cB01 = wyB0*wxB1, cB11 = wyB1*wxB1;

    floatx2 sdrA = {0.f, 0.f}, sgbA = {0.f, 0.f};
    floatx2 sdrB = {0.f, 0.f}, sgbB = {0.f, 0.f};

    acc2(eA0.x, wzA0*cA00, sdrA, sgbA);
    acc2(eA0.y, wzA0*cA10, sdrA, sgbA);
    acc2(eA0.z, wzA0*cA01, sdrA, sgbA);
    acc2(eA0.w, wzA0*cA11, sdrA, sgbA);
    acc2(eA1.x, wzA1*cA00, sdrA, sgbA);
    acc2(eA1.y, wzA1*cA10, sdrA, sgbA);
    acc2(eA1.z, wzA1*cA01, sdrA, sgbA);
    acc2(eA1.w, wzA1*cA11, sdrA, sgbA);

    acc2(eB0.x, wzB0*cB00, sdrB, sgbB);
    acc2(eB0.y, wzB0*cB10, sdrB, sgbB);
    acc2(eB0.z, wzB0*cB01, sdrB, sgbB);
    acc2(eB0.w, wzB0*cB11, sdrB, sgbB);
    acc2(eB1.x, wzB1*cB00, sdrB, sgbB);
    acc2(eB1.y, wzB1*cB10, sdrB, sgbB);
    acc2(eB1.z, wzB1*cB01, sdrB, sgbB);
    acc2(eB1.w, wzB1*cB11, sdrB, sgbB);

    // density = 1 - (1+e^a)^(-interval) = 1 - 2^(-interval * log2(1 + 2^(a*log2e)))
    {
        const float a  = sdrA.x + ACT_SHIFT;
        const float ea = __builtin_amdgcn_exp2f(LOG2E * a);
        const float L  = __builtin_amdgcn_logf(1.0f + ea);
        lds_den[src0] = 1.0f - __builtin_amdgcn_exp2f(-interval * L);
        const float e1 = __builtin_amdgcn_exp2f(-LOG2E * sdrA.y);
        const float e2 = __builtin_amdgcn_exp2f(-LOG2E * sgbA.x);
        const float e3 = __builtin_amdgcn_exp2f(-LOG2E * sgbA.y);
        lds_r[src0] = __builtin_amdgcn_rcpf(1.0f + e1);
        lds_g[src0] = __builtin_amdgcn_rcpf(1.0f + e2);
        lds_b[src0] = __builtin_amdgcn_rcpf(1.0f + e3);
    }
    {
        const float a  = sdrB.x + ACT_SHIFT;
        const float ea = __builtin_amdgcn_exp2f(LOG2E * a);
        const float L  = __builtin_amdgcn_logf(1.0f + ea);
        lds_den[src1] = 1.0f - __builtin_amdgcn_exp2f(-interval * L);
        const float e1 = __builtin_amdgcn_exp2f(-LOG2E * sdrB.y);
        const float e2 = __builtin_amdgcn_exp2f(-LOG2E * sgbB.x);
        const float e3 = __builtin_amdgcn_exp2f(-LOG2E * sgbB.y);
        lds_r[src1] = __builtin_amdgcn_rcpf(1.0f + e1);
        lds_g[src1] = __builtin_amdgcn_rcpf(1.0f + e2);
        lds_b[src1] = __builtin_amdgcn_rcpf(1.0f + e3);
    }
    __syncthreads();

    // fully coalesced writes in natural order
    out_density[base + tid]       = lds_den[tid];
    out_density[base + tid + 128] = lds_den[tid + 128];
    const int cb = base * 3;
    #pragma unroll
    for (int k = 0; k < 6; ++k) {
        const int o  = k * 128 + tid;
        const int pp = o / 3;
        const int cc = o - pp * 3;
        const float vr = lds_r[pp], vg = lds_g[pp], vb = lds_b[pp];
        out_color[cb + o] = (cc == 0) ? vr : ((cc == 1) ? vg : vb);
    }
}

// ---------------- fallback: direct SoA sampling (round-2 kernel) ----------------
__device__ __forceinline__ float2 ld2(const float* p) {
    return *reinterpret_cast<const float2*>(p);
}

__global__ __launch_bounds__(256)
void dvgo_render_kernel(const float* __restrict__ origins,
                        const float* __restrict__ directions,
                        const float* __restrict__ lengths,
                        const float* __restrict__ dgrid,
                        const float* __restrict__ cgrid,
                        float* __restrict__ out_density,
                        float* __restrict__ out_color)
{
    const int r = blockIdx.x;
    const int p = threadIdx.x;
    const int idx = r * NPTS + p;

    const float t  = lengths[idx];
    const float ox = origins[3*r+0], oy = origins[3*r+1], oz = origins[3*r+2];
    const float dx = directions[3*r+0], dy = directions[3*r+1], dz = directions[3*r+2];
    const float interval = sqrtf(dx*dx + dy*dy + dz*dz);

    const float x = ox + dx*t;
    const float y = oy + dy*t;
    const float z = oz + dz*t;

    const float half_sm1 = 0.5f * (float)(GS - 1);
    const float px = (x + 1.0f) * half_sm1;
    const float py = (y + 1.0f) * half_sm1;
    const float pz = (z + 1.0f) * half_sm1;

    const float fx = floorf(px), fy = floorf(py), fz = floorf(pz);
    const float wx1 = px - fx, wy1 = py - fy, wz1 = pz - fz;
    const float wx0 = 1.0f - wx1, wy0 = 1.0f - wy1, wz0 = 1.0f - wz1;

    int x0 = (int)fx, y0 = (int)fy, z0 = (int)fz;
    x0 = min(max(x0, 0), GS-2);
    y0 = min(max(y0, 0), GS-2);
    z0 = min(max(z0, 0), GS-2);

    int rows[4];
    rows[0] = ((z0  )*GS + y0  )*GS + x0;
    rows[1] = ((z0  )*GS + y0+1)*GS + x0;
    rows[2] = ((z0+1)*GS + y0  )*GS + x0;
    rows[3] = ((z0+1)*GS + y0+1)*GS + x0;

    const float* bases[4] = {dgrid, cgrid, cgrid + GS3, cgrid + 2*GS3};

    float2 v[4][4];
    #pragma unroll
    for (int ch = 0; ch < 4; ++ch)
        #pragma unroll
        for (int rr = 0; rr < 4; ++rr)
            v[ch][rr] = ld2(bases[ch] + rows[rr]);

    float rw[4];
    rw[0] = wz0*wy0; rw[1] = wz0*wy1; rw[2] = wz1*wy0; rw[3] = wz1*wy1;

    float s[4];
    #pragma unroll
    for (int ch = 0; ch < 4; ++ch) {
        float acc = 0.0f;
        #pragma unroll
        for (int rr = 0; rr < 4; ++rr)
            acc = fmaf(rw[rr], fmaf(v[ch][rr].x, wx0, v[ch][rr].y * wx1), acc);
        s[ch] = acc;
    }

    const float a  = s[0] + ACT_SHIFT;
    const float sp = (a > 20.0f) ? a : log1pf(__expf(a));
    out_density[idx] = 1.0f - __expf(-interval * sp);

    #pragma unroll
    for (int c = 0; c < 3; ++c)
        out_color[idx*3 + c] = 1.0f / (1.0f + __expf(-s[c+1]));
}

extern "C" void kernel_launch(void* const* d_in, const int* in_sizes, int n_in,
                              void* d_out, int out_size, void* d_ws, size_t ws_size,
                              hipStream_t stream) {
    const float* origins    = (const float*)d_in[0];
    const float* directions = (const float*)d_in[1];
    const float* lengths    = (const float*)d_in[2];
    const float* dgrid      = (const float*)d_in[3];
    const float* cgrid      = (const float*)d_in[4];

    float* out_density = (float*)d_out;               // [R, P, 1]
    float* out_color   = (float*)d_out + NRAYS*NPTS;  // [R, P, 3]

    if (ws_size >= (size_t)GS3 * sizeof(uint4)) {
        uint4* quads = (uint4*)d_ws;
        repack_fp8quad_kernel<<<(GS3 + 255) / 256, 256, 0, stream>>>(dgrid, cgrid, quads);
        sample_fp8_x2_kernel<<<NRAYS, 128, 0, stream>>>(
            origins, directions, lengths, quads, out_density, out_color);
    } else {
        dvgo_render_kernel<<<NRAYS, NPTS, 0, stream>>>(
            origins, directions, lengths, dgrid, cgrid, out_density, out_color);
    }
}

// Round 10
// 56.223 us; speedup vs baseline: 1.0770x; 1.0264x over previous
//
#include <hip/hip_runtime.h>
#include <math.h>

#define NRAYS 16384
#define NPTS  256
#define GS    160
#define GS3   (GS*GS*GS)

// ACT_SHIFT = log(1/(1-1e-6) - 1) computed in double precision
#define ACT_SHIFT (-13.815509557963774f)
#define LOG2E     (1.4426950408889634f)

typedef float floatx2 __attribute__((ext_vector_type(2)));

// pack 4 floats -> 4 fp8 e4m3 (OCP on gfx950) in one dword, HW RNE rounding
__device__ __forceinline__ unsigned int pack4fp8(float d, float r, float g, float b) {
    int w = __builtin_amdgcn_cvt_pk_fp8_f32(d, r, 0, false);   // bytes 0,1
    w     = __builtin_amdgcn_cvt_pk_fp8_f32(g, b, w, true);    // bytes 2,3
    return (unsigned int)w;
}

// unpack one corner word (4 fp8 channels), packed-f32 accumulate (v_pk_fma_f32)
__device__ __forceinline__ void acc2(unsigned int w, float cw,
                                     floatx2& sdr, floatx2& sgb) {
    floatx2 dr = __builtin_amdgcn_cvt_pk_f32_fp8((int)w, false);  // d, r
    floatx2 gb = __builtin_amdgcn_cvt_pk_f32_fp8((int)w, true);   // g, b
    floatx2 cw2 = {cw, cw};
    sdr += dr * cw2;
    sgb += gb * cw2;
}

// ---- repack: SoA f32 grids -> fp8 xy-quad grid ----
// entry[z][y][x] (16B) = corner words {d,r,g,b} at (y0,x0),(y1,x0),(y0,x1),(y1,x1).
// A point needs only entries (z0,y0,x0) and (z1,y0,x0): 2 aligned dwordx4 gathers.
__global__ __launch_bounds__(256)
void repack_fp8quad_kernel(const float* __restrict__ dgrid,
                           const float* __restrict__ cgrid,
                           uint4* __restrict__ out)
{
    const int i = blockIdx.x * 256 + threadIdx.x;
    if (i >= GS3) return;
    const int x = i % GS;
    const int y = (i / GS) % GS;
    const int ox = (x < GS - 1) ? 1  : 0;   // x+1 (dup at edge, never sampled)
    const int oy = (y < GS - 1) ? GS : 0;   // y+1

    const int i00 = i, i10 = i + oy, i01 = i + ox, i11 = i + oy + ox;

    uint4 v;
    v.x = pack4fp8(dgrid[i00], cgrid[i00], cgrid[GS3 + i00], cgrid[2*GS3 + i00]);
    v.y = pack4fp8(dgrid[i10], cgrid[i10], cgrid[GS3 + i10], cgrid[2*GS3 + i10]);
    v.z = pack4fp8(dgrid[i01], cgrid[i01], cgrid[GS3 + i01], cgrid[2*GS3 + i01]);
    v.w = pack4fp8(dgrid[i11], cgrid[i11], cgrid[GS3 + i11], cgrid[2*GS3 + i11]);
    out[i] = v;
}

// ---- sample: UNSORTED, 2 divergent gathers/point, no LDS/barriers.
// TA model: 2 instrs x ~64 lines = ~13.7 us serialization, overlapped with
// VALU (~10 us) and HBM (~18 us). Sort machinery (~15 us) removed: with only
// 2 gather instrs it costs more than the TA time it saves.
__global__ __launch_bounds__(256)
void sample_fp8_direct_kernel(const float* __restrict__ origins,
                              const float* __restrict__ directions,
                              const float* __restrict__ lengths,
                              const uint4* __restrict__ grid,
                              float* __restrict__ out_density,
                              float* __restrict__ out_color)
{
    const int r   = blockIdx.x;
    const int p   = threadIdx.x;
    const int idx = r * NPTS + p;

    const float t  = lengths[idx];
    const float ox = origins[3*r+0], oy = origins[3*r+1], oz = origins[3*r+2];
    const float dx = directions[3*r+0], dy = directions[3*r+1], dz = directions[3*r+2];
    const float interval = sqrtf(dx*dx + dy*dy + dz*dz);

    // map [-1,1] -> [0, GS-1] (align_corners=True)
    const float half_sm1 = 0.5f * (float)(GS - 1);
    const float px = (ox + dx*t + 1.0f) * half_sm1;
    const float py = (oy + dy*t + 1.0f) * half_sm1;
    const float pz = (oz + dz*t + 1.0f) * half_sm1;

    const float fx = floorf(px), fy = floorf(py), fz = floorf(pz);

    int x0 = min(max((int)fx, 0), GS-2);
    int y0 = min(max((int)fy, 0), GS-2);
    int z0 = min(max((int)fz, 0), GS-2);

    const int i0 = (z0*GS + y0)*GS + x0;

    // the two gathers (all 8 corners x 4 channels)
    const uint4 ez0 = grid[i0];
    const uint4 ez1 = grid[i0 + GS*GS];

    // weights (computed while loads are in flight)
    const float wx1 = px - fx, wy1 = py - fy, wz1 = pz - fz;
    const float wx0 = 1.0f - wx1, wy0 = 1.0f - wy1, wz0 = 1.0f - wz1;
    const float c00 = wy0*wx0, c10 = wy1*wx0, c01 = wy0*wx1, c11 = wy1*wx1;

    floatx2 sdr = {0.f, 0.f}, sgb = {0.f, 0.f};
    acc2(ez0.x, wz0*c00, sdr, sgb);
    acc2(ez0.y, wz0*c10, sdr, sgb);
    acc2(ez0.z, wz0*c01, sdr, sgb);
    acc2(ez0.w, wz0*c11, sdr, sgb);
    acc2(ez1.x, wz1*c00, sdr, sgb);
    acc2(ez1.y, wz1*c10, sdr, sgb);
    acc2(ez1.z, wz1*c01, sdr, sgb);
    acc2(ez1.w, wz1*c11, sdr, sgb);

    // density = 1 - (1+e^a)^(-interval) = 1 - 2^(-interval * log2(1 + 2^(a*log2e)))
    const float a  = sdr.x + ACT_SHIFT;
    const float ea = __builtin_amdgcn_exp2f(LOG2E * a);
    const float L  = __builtin_amdgcn_logf(1.0f + ea);
    out_density[idx] = 1.0f - __builtin_amdgcn_exp2f(-interval * L);

    // sigmoid via native exp2 + rcp
    const float e1 = __builtin_amdgcn_exp2f(-LOG2E * sdr.y);
    const float e2 = __builtin_amdgcn_exp2f(-LOG2E * sgb.x);
    const float e3 = __builtin_amdgcn_exp2f(-LOG2E * sgb.y);
    out_color[idx*3 + 0] = __builtin_amdgcn_rcpf(1.0f + e1);
    out_color[idx*3 + 1] = __builtin_amdgcn_rcpf(1.0f + e2);
    out_color[idx*3 + 2] = __builtin_amdgcn_rcpf(1.0f + e3);
}

// ---------------- fallback: direct SoA sampling (round-2 kernel) ----------------
__device__ __forceinline__ float2 ld2(const float* p) {
    return *reinterpret_cast<const float2*>(p);
}

__global__ __launch_bounds__(256)
void dvgo_render_kernel(const float* __restrict__ origins,
                        const float* __restrict__ directions,
                        const float* __restrict__ lengths,
                        const float* __restrict__ dgrid,
                        const float* __restrict__ cgrid,
                        float* __restrict__ out_density,
                        float* __restrict__ out_color)
{
    const int r = blockIdx.x;
    const int p = threadIdx.x;
    const int idx = r * NPTS + p;

    const float t  = lengths[idx];
    const float ox = origins[3*r+0], oy = origins[3*r+1], oz = origins[3*r+2];
    const float dx = directions[3*r+0], dy = directions[3*r+1], dz = directions[3*r+2];
    const float interval = sqrtf(dx*dx + dy*dy + dz*dz);

    const float x = ox + dx*t;
    const float y = oy + dy*t;
    const float z = oz + dz*t;

    const float half_sm1 = 0.5f * (float)(GS - 1);
    const float px = (x + 1.0f) * half_sm1;
    const float py = (y + 1.0f) * half_sm1;
    const float pz = (z + 1.0f) * half_sm1;

    const float fx = floorf(px), fy = floorf(py), fz = floorf(pz);
    const float wx1 = px - fx, wy1 = py - fy, wz1 = pz - fz;
    const float wx0 = 1.0f - wx1, wy0 = 1.0f - wy1, wz0 = 1.0f - wz1;

    int x0 = (int)fx, y0 = (int)fy, z0 = (int)fz;
    x0 = min(max(x0, 0), GS-2);
    y0 = min(max(y0, 0), GS-2);
    z0 = min(max(z0, 0), GS-2);

    int rows[4];
    rows[0] = ((z0  )*GS + y0  )*GS + x0;
    rows[1] = ((z0  )*GS + y0+1)*GS + x0;
    rows[2] = ((z0+1)*GS + y0  )*GS + x0;
    rows[3] = ((z0+1)*GS + y0+1)*GS + x0;

    const float* bases[4] = {dgrid, cgrid, cgrid + GS3, cgrid + 2*GS3};

    float2 v[4][4];
    #pragma unroll
    for (int ch = 0; ch < 4; ++ch)
        #pragma unroll
        for (int rr = 0; rr < 4; ++rr)
            v[ch][rr] = ld2(bases[ch] + rows[rr]);

    float rw[4];
    rw[0] = wz0*wy0; rw[1] = wz0*wy1; rw[2] = wz1*wy0; rw[3] = wz1*wy1;

    float s[4];
    #pragma unroll
    for (int ch = 0; ch < 4; ++ch) {
        float acc = 0.0f;
        #pragma unroll
        for (int rr = 0; rr < 4; ++rr)
            acc = fmaf(rw[rr], fmaf(v[ch][rr].x, wx0, v[ch][rr].y * wx1), acc);
        s[ch] = acc;
    }

    const float a  = s[0] + ACT_SHIFT;
    const float sp = (a > 20.0f) ? a : log1pf(__expf(a));
    out_density[idx] = 1.0f - __expf(-interval * sp);

    #pragma unroll
    for (int c = 0; c < 3; ++c)
        out_color[idx*3 + c] = 1.0f / (1.0f + __expf(-s[c+1]));
}

extern "C" void kernel_launch(void* const* d_in, const int* in_sizes, int n_in,
                              void* d_out, int out_size, void* d_ws, size_t ws_size,
                              hipStream_t stream) {
    const float* origins    = (const float*)d_in[0];
    const float* directions = (const float*)d_in[1];
    const float* lengths    = (const float*)d_in[2];
    const float* dgrid      = (const float*)d_in[3];
    const float* cgrid      = (const float*)d_in[4];

    float* out_density = (float*)d_out;               // [R, P, 1]
    float* out_color   = (float*)d_out + NRAYS*NPTS;  // [R, P, 3]

    if (ws_size >= (size_t)GS3 * sizeof(uint4)) {
        uint4* quads = (uint4*)d_ws;
        repack_fp8quad_kernel<<<(GS3 + 255) / 256, 256, 0, stream>>>(dgrid, cgrid, quads);
        sample_fp8_direct_kernel<<<NRAYS, NPTS, 0, stream>>>(
            origins, directions, lengths, quads, out_density, out_color);
    } else {
        dvgo_render_kernel<<<NRAYS, NPTS, 0, stream>>>(
            origins, directions, lengths, dgrid, cgrid, out_density, out_color);
    }
}